// Round 17
// baseline (652.446 us; speedup 1.0000x reference)
//
#include <hip/hip_runtime.h>
#include <hip/hip_bf16.h>
#include <cstdint>

constexpr int IN_DIM = 768;
constexpr int FB_ENT = 0;     // 96 frags: W_ent (768x64)
constexpr int FB_L0  = 96;    // 32 frags: [Wf0;Wb0] stacked (256x64)
constexpr int FB_L1  = 128;   // 32 frags: [Wf1;Wb1] stacked (256x64)
constexpr int NFRAG  = 160;

typedef __attribute__((ext_vector_type(8))) short bf16x8;
typedef __attribute__((ext_vector_type(4))) float f32x4;

static __device__ __forceinline__ float leaky_(float x){ return x >= 0.0f ? x : 0.01f * x; }

static __device__ __forceinline__ float wsum_(float v){
#pragma unroll
  for (int m = 1; m < 64; m <<= 1) v += __shfl_xor(v, m, 64);
  return v;
}

static __device__ __forceinline__ float wln_(float v, float g, float be){
  float mu  = wsum_(v) * 0.015625f;
  float c   = v - mu;
  float var = wsum_(c * c) * 0.015625f;
  return c * rsqrtf(var + 1e-5f) * g + be;
}

// DPP row_ror<N> add: x += ror_N(x) within each 16-lane row (full-rate VALU).
template<int CTRL>
static __device__ __forceinline__ float dpp_radd(float x){
  const int t = __builtin_amdgcn_update_dpp(0, __float_as_int(x), CTRL, 0xf, 0xf, true);
  return x + __int_as_float(t);
}
static __device__ __forceinline__ float rowsum16_(float x){
  x = dpp_radd<0x121>(x);  // ror:1
  x = dpp_radd<0x122>(x);  // ror:2
  x = dpp_radd<0x124>(x);  // ror:4
  x = dpp_radd<0x128>(x);  // ror:8
  return x;
}

static __device__ __forceinline__ unsigned short f2bf(float x){
  return __bfloat16_as_ushort(__float2bfloat16(x));
}
static __device__ __forceinline__ float bf2f(unsigned short u){
  return __bfloat162float(__ushort_as_bfloat16(u));
}
static __device__ __forceinline__ void split4(const float4 a, ushort4& hi, ushort4& lo){
  hi.x = f2bf(a.x); lo.x = f2bf(a.x - bf2f(hi.x));
  hi.y = f2bf(a.y); lo.y = f2bf(a.y - bf2f(hi.y));
  hi.z = f2bf(a.z); lo.z = f2bf(a.z - bf2f(hi.z));
  hi.w = f2bf(a.w); lo.w = f2bf(a.w - bf2f(hi.w));
}

static __device__ __forceinline__ f32x4 mfma3(bf16x8 ah, bf16x8 al, bf16x8 wh, bf16x8 wl, f32x4 acc){
  acc = __builtin_amdgcn_mfma_f32_16x16x32_bf16(ah, wh, acc, 0, 0, 0);
  acc = __builtin_amdgcn_mfma_f32_16x16x32_bf16(al, wh, acc, 0, 0, 0);
  acc = __builtin_amdgcn_mfma_f32_16x16x32_bf16(ah, wl, acc, 0, 0, 0);
  return acc;
}

// ---------------- weight prep: split-bf16 frag tables ----------------
__global__ __launch_bounds__(256) void k_wprep(
    const float* __restrict__ Went, const float* __restrict__ Wf,
    const float* __restrict__ Wb,
    unsigned short* __restrict__ Fhi, unsigned short* __restrict__ Flo)
{
  const int gt = blockIdx.x * 256 + threadIdx.x;
  if (gt >= NFRAG * 64) return;
  const int fid = gt >> 6, lane = gt & 63;
  int kind, lf;
  if (fid < FB_L0)      { kind = 0; lf = fid; }
  else if (fid < FB_L1) { kind = 1; lf = fid - FB_L0; }
  else                  { kind = 2; lf = fid - FB_L1; }
  const int kt = lf >> 2, nn = lf & 3;
  const int col = nn * 16 + (lane & 15);
  const int r0  = kt * 32 + (lane >> 4) * 8;
  unsigned short* ph = Fhi + ((size_t)fid << 9) + lane * 8;
  unsigned short* pl = Flo + ((size_t)fid << 9) + lane * 8;
#pragma unroll
  for (int j = 0; j < 8; ++j){
    const int gr = r0 + j;
    const float* rp;
    if (kind == 0)      rp = Went + (size_t)gr * 64;
    else if (kind == 1) rp = (gr < 128) ? Wf + (size_t)gr * 64
                                        : Wb + (size_t)(gr - 128) * 64;
    else                rp = (gr < 128) ? Wf + (size_t)(128 + gr) * 64
                                        : Wb + (size_t)gr * 64;
    const float v = rp[col];
    const unsigned short h = f2bf(v);
    ph[j] = h;
    pl[j] = f2bf(v - bf2f(h));
  }
}

// ---------------- FUSED: entity encoder (MFMA) + CSR slot scatter ----------------
// Blocks [0, encBlocks): H0=H=LN(leaky(X@Went+b)) for 64 rows each.
// Blocks [encBlocks, ...): counting-sort scatter, 4 edges/thread batched chains.
__global__ __launch_bounds__(256) void k_encslot(const float* __restrict__ X,
    const unsigned short* __restrict__ Fhi, const unsigned short* __restrict__ Flo,
    const float* __restrict__ b, const float* __restrict__ g_,
    const float* __restrict__ be, float* __restrict__ o0, float* __restrict__ o1,
    int nrows, int encBlocks,
    const int* __restrict__ ht, const int* __restrict__ rt,
    int* __restrict__ posf, int* __restrict__ posb,
    unsigned* __restrict__ si, int M)
{
  __shared__ unsigned short Ahi[64 * 128];
  __shared__ unsigned short Alo[64 * 128];
  const int bid = blockIdx.x;
  const int tid = threadIdx.x;

  if (bid >= encBlocks){
    // ---- slot scatter, 4 edges/thread: si[slot] = src | (rt << 16) ----
    const int m0 = (bid - encBlocks) * 1024;
    int hv[4], tv[4]; unsigned rsh[4]; bool act[4];
#pragma unroll
    for (int j = 0; j < 4; ++j){
      const int m = m0 + j * 256 + tid;
      act[j] = (m < M);
      const int mm = act[j] ? m : 0;
      hv[j] = ht[2*mm]; tv[j] = ht[2*mm+1];
      rsh[j] = ((unsigned)rt[mm]) << 16;
    }
    int sfi[4], sbi[4];
#pragma unroll
    for (int j = 0; j < 4; ++j) if (act[j]) sfi[j] = atomicAdd(&posf[tv[j]], 1);
#pragma unroll
    for (int j = 0; j < 4; ++j) if (act[j]) sbi[j] = atomicAdd(&posb[hv[j]], 1);
#pragma unroll
    for (int j = 0; j < 4; ++j) if (act[j]) si[sfi[j]] = (unsigned)hv[j] | rsh[j];
#pragma unroll
    for (int j = 0; j < 4; ++j) if (act[j]) si[sbi[j]] = (unsigned)tv[j] | rsh[j];
    return;
  }

  // ---- encoder ----
  const int tile = bid * 64;
  const int w = tid >> 6, lane = tid & 63, g = lane >> 4, lr = lane & 15;
  const int rowb = w * 16;

  f32x4 acc[4];
#pragma unroll
  for (int n = 0; n < 4; ++n){
    const float bv = b[n * 16 + lr];
    acc[n] = (f32x4){bv, bv, bv, bv};
  }

  for (int ch = 0; ch < 6; ++ch){
    __syncthreads();
#pragma unroll
    for (int i = 0; i < 8; ++i){
      const int idx = tid + 256 * i;
      const int row = idx >> 5, c = idx & 31;
      int gr = tile + row; if (gr >= nrows) gr = nrows - 1;
      const float4 a = *(const float4*)&X[(size_t)gr * IN_DIM + ch * 128 + c * 4];
      ushort4 hi, lo; split4(a, hi, lo);
      const int ad = (row * 256 + c * 8) ^ ((row & 7) << 4);
      *(ushort4*)((char*)Ahi + ad) = hi;
      *(ushort4*)((char*)Alo + ad) = lo;
    }
    __syncthreads();

    bf16x8 Ah[4], Al[4];
#pragma unroll
    for (int kt = 0; kt < 4; ++kt){
      const int row = rowb + lr;
      const int ad = (row * 256 + kt * 64 + g * 16) ^ ((row & 7) << 4);
      Ah[kt] = *(const bf16x8*)((const char*)Ahi + ad);
      Al[kt] = *(const bf16x8*)((const char*)Alo + ad);
    }
    const int fb = ch * 16;
#pragma unroll
    for (int n = 0; n < 4; ++n)
#pragma unroll
      for (int kt = 0; kt < 4; ++kt){
        const size_t fo = (((size_t)(fb + kt * 4 + n)) << 9) + lane * 8;
        acc[n] = mfma3(Ah[kt], Al[kt], *(const bf16x8*)(Fhi + fo), *(const bf16x8*)(Flo + fo), acc[n]);
      }
  }

#pragma unroll
  for (int reg = 0; reg < 4; ++reg){
    const int lrow = rowb + g * 4 + reg;
    float v[4];
#pragma unroll
    for (int n = 0; n < 4; ++n) v[n] = leaky_(acc[n][reg]);
    float s = v[0] + v[1] + v[2] + v[3];
#pragma unroll
    for (int msk = 1; msk < 16; msk <<= 1) s += __shfl_xor(s, msk, 64);
    const float mu = s * 0.015625f;
    float q = 0.f;
#pragma unroll
    for (int n = 0; n < 4; ++n){ v[n] -= mu; q += v[n] * v[n]; }
#pragma unroll
    for (int msk = 1; msk < 16; msk <<= 1) q += __shfl_xor(q, msk, 64);
    const float rs = rsqrtf(q * 0.015625f + 1e-5f);
    const int r = tile + lrow;
    if (r < nrows){
#pragma unroll
      for (int n = 0; n < 4; ++n){
        const int col = n * 16 + lr;
        const float o = v[n] * rs * g_[col] + be[col];
        o0[(size_t)r * 64 + col] = o;
        o1[(size_t)r * 64 + col] = o;
      }
    }
  }
}

// ---------------- H update (MFMA): H = LN(leaky((Sall@[Wf;Wb]+cf*bf+cb*bb)/cnt)+H) ----
__global__ __launch_bounds__(256) void k_hupd2m(float* __restrict__ H,
    const float* __restrict__ Sall,
    const int* __restrict__ cf, const int* __restrict__ cb,
    const unsigned short* __restrict__ Fhi, const unsigned short* __restrict__ Flo, int fb,
    const float* __restrict__ bf, const float* __restrict__ bb,
    const float* __restrict__ g_, const float* __restrict__ be, int N)
{
  __shared__ unsigned short Ahi[64 * 256];
  __shared__ unsigned short Alo[64 * 256];
  const int tile = blockIdx.x * 64, tid = threadIdx.x;
#pragma unroll
  for (int i = 0; i < 16; ++i){
    const int idx = tid + 256 * i;
    const int row = idx >> 6, c = idx & 63;
    int gr = tile + row; if (gr >= N) gr = N - 1;
    const float4 a = *(const float4*)&Sall[(size_t)gr * 256 + c * 4];
    ushort4 hi, lo; split4(a, hi, lo);
    const int ad = (row * 512 + c * 8) ^ ((row & 7) << 4);
    *(ushort4*)((char*)Ahi + ad) = hi;
    *(ushort4*)((char*)Alo + ad) = lo;
  }
  __syncthreads();

  const int w = tid >> 6, lane = tid & 63, g = lane >> 4, lr = lane & 15;
  const int rowb = w * 16;
  bf16x8 Ah[8], Al[8];
#pragma unroll
  for (int kt = 0; kt < 8; ++kt){
    const int row = rowb + lr;
    const int ad = (row * 512 + kt * 64 + g * 16) ^ ((row & 7) << 4);
    Ah[kt] = *(const bf16x8*)((const char*)Ahi + ad);
    Al[kt] = *(const bf16x8*)((const char*)Alo + ad);
  }

  int cfv[4], cbv[4];
#pragma unroll
  for (int reg = 0; reg < 4; ++reg){
    int r = tile + rowb + g * 4 + reg; if (r >= N) r = N - 1;
    cfv[reg] = cf[r]; cbv[reg] = cb[r];
  }
  f32x4 acc[4];
#pragma unroll
  for (int n = 0; n < 4; ++n){
    const float bfc = bf[n * 16 + lr], bbc = bb[n * 16 + lr];
#pragma unroll
    for (int reg = 0; reg < 4; ++reg)
      acc[n][reg] = (float)cfv[reg] * bfc + (float)cbv[reg] * bbc;
  }
#pragma unroll
  for (int n = 0; n < 4; ++n)
#pragma unroll
    for (int kt = 0; kt < 8; ++kt){
      const size_t fo = (((size_t)(fb + kt * 4 + n)) << 9) + lane * 8;
      acc[n] = mfma3(Ah[kt], Al[kt], *(const bf16x8*)(Fhi + fo), *(const bf16x8*)(Flo + fo), acc[n]);
    }

#pragma unroll
  for (int reg = 0; reg < 4; ++reg){
    const int lrow = rowb + g * 4 + reg;
    const int r = tile + lrow;
    const int rr = (r < N) ? r : N - 1;
    const float c = (float)(cfv[reg] + cbv[reg]);
    float v[4];
#pragma unroll
    for (int n = 0; n < 4; ++n)
      v[n] = leaky_(acc[n][reg] / c) + H[(size_t)rr * 64 + n * 16 + lr];
    float s = v[0] + v[1] + v[2] + v[3];
#pragma unroll
    for (int msk = 1; msk < 16; msk <<= 1) s += __shfl_xor(s, msk, 64);
    const float mu = s * 0.015625f;
    float q = 0.f;
#pragma unroll
    for (int n = 0; n < 4; ++n){ v[n] -= mu; q += v[n] * v[n]; }
#pragma unroll
    for (int msk = 1; msk < 16; msk <<= 1) q += __shfl_xor(q, msk, 64);
    const float rs = rsqrtf(q * 0.015625f + 1e-5f);
    if (r < N){
#pragma unroll
      for (int n = 0; n < 4; ++n){
        const int col = n * 16 + lr;
        H[(size_t)r * 64 + col] = v[n] * rs * g_[col] + be[col];
      }
    }
  }
}

// ---------------- f32 encoder (rel table, 500 rows) ----------------
__global__ __launch_bounds__(256) void k_enc(const float* __restrict__ X,
    const float* __restrict__ W, const float* __restrict__ b,
    const float* __restrict__ g, const float* __restrict__ be,
    float* __restrict__ o0, float* __restrict__ o1, int nrows)
{
  const int w = threadIdx.x >> 6, d = threadIdx.x & 63;
  const int rbase = blockIdx.x * 16 + w * 4;
  int rows[4];
#pragma unroll
  for (int j = 0; j < 4; ++j){ int r = rbase + j; rows[j] = r < nrows ? r : nrows - 1; }
  float acc[4] = {0.f, 0.f, 0.f, 0.f};
  for (int k4 = 0; k4 < IN_DIM / 4; ++k4){
    const int k = k4 * 4;
    const float w0 = W[(k+0)*64+d], w1 = W[(k+1)*64+d];
    const float w2 = W[(k+2)*64+d], w3 = W[(k+3)*64+d];
#pragma unroll
    for (int j = 0; j < 4; ++j){
      const float4 a = *(const float4*)&X[(size_t)rows[j] * IN_DIM + k];
      acc[j] = fmaf(a.x, w0, fmaf(a.y, w1, fmaf(a.z, w2, fmaf(a.w, w3, acc[j]))));
    }
  }
#pragma unroll
  for (int j = 0; j < 4; ++j){
    const int r = rbase + j;
    if (r < nrows){
      float v = wln_(leaky_(acc[j] + b[d]), g[d], be[d]);
      o0[(size_t)r*64+d] = v;
      if (o1) o1[(size_t)r*64+d] = v;
    }
  }
}

// Dual matmul: HWp[r][0:64] = X[r]@W1 ; HWp[r][64:128] = X[r]@W3
__global__ __launch_bounds__(256) void k_xw2(const float* __restrict__ X,
    const float* __restrict__ W1, const float* __restrict__ W3,
    float* __restrict__ Y, int nrows)
{
  const int w = threadIdx.x >> 6, d = threadIdx.x & 63;
  const int rbase = blockIdx.x * 16 + w * 4;
  int rows[4];
#pragma unroll
  for (int j = 0; j < 4; ++j){ int r = rbase + j; rows[j] = r < nrows ? r : nrows - 1; }
  float a1[4] = {0.f,0.f,0.f,0.f}, a3[4] = {0.f,0.f,0.f,0.f};
  for (int k4 = 0; k4 < 16; ++k4){
    const int k = k4 * 4;
    const float u0 = W1[(k+0)*64+d], u1 = W1[(k+1)*64+d];
    const float u2 = W1[(k+2)*64+d], u3 = W1[(k+3)*64+d];
    const float v0 = W3[(k+0)*64+d], v1 = W3[(k+1)*64+d];
    const float v2 = W3[(k+2)*64+d], v3 = W3[(k+3)*64+d];
#pragma unroll
    for (int j = 0; j < 4; ++j){
      const float4 a = *(const float4*)&X[(size_t)rows[j] * 64 + k];
      a1[j] = fmaf(a.x, u0, fmaf(a.y, u1, fmaf(a.z, u2, fmaf(a.w, u3, a1[j]))));
      a3[j] = fmaf(a.x, v0, fmaf(a.y, v1, fmaf(a.z, v2, fmaf(a.w, v3, a3[j]))));
    }
  }
#pragma unroll
  for (int j = 0; j < 4; ++j){
    const int r = rbase + j;
    if (r < nrows){
      Y[(size_t)r * 128 + d]      = a1[j];
      Y[(size_t)r * 128 + 64 + d] = a3[j];
    }
  }
}

// TE pack: TEP[r*64+d] = { (E0t@euW2+eu_b)[r][d], E0t[r][d] }
__global__ __launch_bounds__(256) void k_tep(const float* __restrict__ E0t,
    const float* __restrict__ W, const float* __restrict__ bias,
    float2* __restrict__ TEP, int nrows)
{
  const int w = threadIdx.x >> 6, d = threadIdx.x & 63;
  const int rbase = blockIdx.x * 16 + w * 4;
  int rows[4];
#pragma unroll
  for (int j = 0; j < 4; ++j){ int r = rbase + j; rows[j] = r < nrows ? r : nrows - 1; }
  const float b0 = bias[d];
  float acc[4] = {b0, b0, b0, b0};
  for (int k4 = 0; k4 < 16; ++k4){
    const int k = k4 * 4;
    const float w0 = W[(k+0)*64+d], w1 = W[(k+1)*64+d];
    const float w2 = W[(k+2)*64+d], w3 = W[(k+3)*64+d];
#pragma unroll
    for (int j = 0; j < 4; ++j){
      const float4 a = *(const float4*)&E0t[(size_t)rows[j] * 64 + k];
      acc[j] = fmaf(a.x, w0, fmaf(a.y, w1, fmaf(a.z, w2, fmaf(a.w, w3, acc[j]))));
    }
  }
#pragma unroll
  for (int j = 0; j < 4; ++j){
    const int r = rbase + j;
    if (r < nrows) TEP[(size_t)r * 64 + d] = make_float2(acc[j], E0t[(size_t)r * 64 + d]);
  }
}

// Degree counts
__global__ __launch_bounds__(256) void k_cnt(const int* __restrict__ ht,
    int* __restrict__ cf, int* __restrict__ cb, int M)
{
  int m = blockIdx.x * 256 + threadIdx.x;
  if (m < M){
    atomicAdd(&cf[ht[2*m+1]], 1);
    atomicAdd(&cb[ht[2*m+0]], 1);
  }
}

// ---- parallel exclusive scan over a single count array ----
__global__ __launch_bounds__(256) void k_scan1(const int* __restrict__ c,
    int* __restrict__ pos, int* __restrict__ bsum, int N)
{
  __shared__ int ws[4];
  const int tid = threadIdx.x, lane = tid & 63, w = tid >> 6;
  const int i = blockIdx.x * 256 + tid;
  const int v = (i < N) ? c[i] : 0;
  int inc = v;
#pragma unroll
  for (int off = 1; off < 64; off <<= 1){
    int t = __shfl_up(inc, off, 64);
    if (lane >= off) inc += t;
  }
  if (lane == 63) ws[w] = inc;
  __syncthreads();
  int wbase = 0;
  for (int j = 0; j < w; ++j) wbase += ws[j];
  if (i < N) pos[i] = wbase + inc - v;
  if (tid == 255) bsum[blockIdx.x] = wbase + inc;
}

__global__ __launch_bounds__(256) void k_scan3(int* __restrict__ pos,
    const int* __restrict__ bsum, int N, int offset)
{
  const int i = blockIdx.x * 256 + threadIdx.x;
  if (i < N) pos[i] += bsum[blockIdx.x] + offset;
}

// Generic small single-block exclusive scan (in place).
__global__ __launch_bounds__(256) void k_qscan(int* __restrict__ bcnt, int nb)
{
  __shared__ int ws[4];
  const int tid = threadIdx.x, lane = tid & 63, w = tid >> 6;
  const int chunk = (nb + 255) / 256;
  int s = 0;
  for (int i = 0; i < chunk; ++i){ int idx = tid * chunk + i; if (idx < nb) s += bcnt[idx]; }
  int v = s;
#pragma unroll
  for (int off = 1; off < 64; off <<= 1){ int t = __shfl_up(v, off, 64); if (lane >= off) v += t; }
  if (lane == 63) ws[w] = v;
  __syncthreads();
  int wbase = 0;
  for (int i = 0; i < w; ++i) wbase += ws[i];
  int run = wbase + v - s;
  for (int i = 0; i < chunk; ++i){
    int idx = tid * chunk + i;
    if (idx < nb){ int t = bcnt[idx]; bcnt[idx] = run; run += t; }
  }
}

// Cross-quarter merge (masks 16, 32) for a f32x4 accumulator.
static __device__ __forceinline__ void qmerge_(f32x4& a){
#pragma unroll
  for (int c = 0; c < 4; ++c){
    float x = a[c];
    x += __shfl_xor(x, 16, 64);
    x += __shfl_xor(x, 32, 64);
    a[c] = x;
  }
}

// Layer-0 CSR pull-sum, quarter-wave, split fwd/bwd loops.
__global__ __launch_bounds__(256) void k_sum(const float* __restrict__ H,
    const float* __restrict__ E, const unsigned* __restrict__ si,
    const int* __restrict__ posf_end, const int* __restrict__ posb_end,
    const int* __restrict__ cf, const int* __restrict__ cb,
    float* __restrict__ Sall, int N)
{
  const int w = threadIdx.x >> 6, lane = threadIdx.x & 63;
  const int n = blockIdx.x * 4 + w;
  if (n >= N) return;
  const int q = lane >> 4, l16 = lane & 15;
  f32x4 sf = {0,0,0,0}, ef = {0,0,0,0}, sb = {0,0,0,0}, eb = {0,0,0,0};
  {
    const int end = posf_end[n], start = end - cf[n];
#pragma unroll 2
    for (int i0 = start; i0 < end; i0 += 4){
      int i = i0 + q;
      const bool act = (i < end); if (!act) i = end - 1;
      const unsigned sv = si[i];
      const int src = (int)(sv & 0xffffu), r = (int)(sv >> 16);
      const float4 h4 = *(const float4*)&H[(size_t)src * 64 + l16 * 4];
      const float4 e4 = *(const float4*)&E[(size_t)r * 64 + l16 * 4];
      const float p = act ? 1.f : 0.f;
      sf[0] = fmaf(p, h4.x, sf[0]); sf[1] = fmaf(p, h4.y, sf[1]);
      sf[2] = fmaf(p, h4.z, sf[2]); sf[3] = fmaf(p, h4.w, sf[3]);
      ef[0] = fmaf(p, e4.x, ef[0]); ef[1] = fmaf(p, e4.y, ef[1]);
      ef[2] = fmaf(p, e4.z, ef[2]); ef[3] = fmaf(p, e4.w, ef[3]);
    }
  }
  {
    const int end = posb_end[n], start = end - cb[n];
#pragma unroll 2
    for (int i0 = start; i0 < end; i0 += 4){
      int i = i0 + q;
      const bool act = (i < end); if (!act) i = end - 1;
      const unsigned sv = si[i];
      const int src = (int)(sv & 0xffffu), r = (int)(sv >> 16);
      const float4 h4 = *(const float4*)&H[(size_t)src * 64 + l16 * 4];
      const float4 e4 = *(const float4*)&E[(size_t)r * 64 + l16 * 4];
      const float p = act ? 1.f : 0.f;
      sb[0] = fmaf(p, h4.x, sb[0]); sb[1] = fmaf(p, h4.y, sb[1]);
      sb[2] = fmaf(p, h4.z, sb[2]); sb[3] = fmaf(p, h4.w, sb[3]);
      eb[0] = fmaf(p, e4.x, eb[0]); eb[1] = fmaf(p, e4.y, eb[1]);
      eb[2] = fmaf(p, e4.z, eb[2]); eb[3] = fmaf(p, e4.w, eb[3]);
    }
  }
  qmerge_(sf); qmerge_(ef); qmerge_(sb); qmerge_(eb);
  if (q == 0){
    float* S = Sall + (size_t)n * 256;
    *(f32x4*)&S[      l16 * 4] = sf;
    *(f32x4*)&S[ 64 + l16 * 4] = ef;
    *(f32x4*)&S[128 + l16 * 4] = sb;
    *(f32x4*)&S[192 + l16 * 4] = eb;
  }
}

// Layer-1 CSR pull-sum with fused edge update, quarter-wave, split loops.
__global__ __launch_bounds__(256) void k_sum2(const float* __restrict__ H,
    const float* __restrict__ HWp, const float2* __restrict__ TEP,
    const unsigned* __restrict__ si,
    const int* __restrict__ posf_end, const int* __restrict__ posb_end,
    const int* __restrict__ cf, const int* __restrict__ cb,
    const float* __restrict__ g0, const float* __restrict__ be0,
    float* __restrict__ Sall, int N)
{
  const int w = threadIdx.x >> 6, lane = threadIdx.x & 63;
  const int n = blockIdx.x * 4 + w;
  if (n >= N) return;
  const int q = lane >> 4, l16 = lane & 15;
  const float4 gg4  = *(const float4*)&g0 [l16 * 4];
  const float4 bb4  = *(const float4*)&be0[l16 * 4];
  const float4 h1n4 = *(const float4*)&HWp[(size_t)n * 128 +      l16 * 4];
  const float4 h3n4 = *(const float4*)&HWp[(size_t)n * 128 + 64 + l16 * 4];
  f32x4 sf = {0,0,0,0}, ef = {0,0,0,0}, sb = {0,0,0,0}, eb = {0,0,0,0};

#define SUM2_LOOP(POS_END, CNT, OTH_OFF, N0, N1, N2, N3, SACC, EACC)            \
  {                                                                             \
    const int end = POS_END[n], start = end - CNT[n];                           \
    _Pragma("unroll 2")                                                         \
    for (int i0 = start; i0 < end; i0 += 4){                                    \
      int i = i0 + q;                                                           \
      const bool act = (i < end); if (!act) i = end - 1;                        \
      const unsigned sv = si[i];                                                \
      const int src = (int)(sv & 0xffffu), rr_ = (int)(sv >> 16);               \
      const float4 h4 = *(const float4*)&H[(size_t)src * 64 + l16 * 4];         \
      const float4 o4 = *(const float4*)&HWp[(size_t)src * 128 + OTH_OFF + l16 * 4]; \
      const float* tp = (const float*)&TEP[(size_t)rr_ * 64 + l16 * 4];         \
      const float4 t0 = *(const float4*)&tp[0];                                 \
      const float4 t1 = *(const float4*)&tp[4];                                 \
      float v[4];                                                               \
      v[0] = leaky_(o4.x + N0 + t0.x) + t0.y;                                   \
      v[1] = leaky_(o4.y + N1 + t0.z) + t0.w;                                   \
      v[2] = leaky_(o4.z + N2 + t1.x) + t1.y;                                   \
      v[3] = leaky_(o4.w + N3 + t1.z) + t1.w;                                   \
      float s  = (v[0] + v[1]) + (v[2] + v[3]);                                 \
      float qq = fmaf(v[0], v[0], v[1] * v[1]) + fmaf(v[2], v[2], v[3] * v[3]); \
      s  = rowsum16_(s);                                                        \
      qq = rowsum16_(qq);                                                       \
      const float mu  = s * 0.015625f;                                          \
      const float var = fmaxf(qq * 0.015625f - mu * mu, 0.f);                   \
      const float rsg = rsqrtf(var + 1e-5f);                                    \
      const float p = act ? 1.f : 0.f;                                          \
      SACC[0] = fmaf(p, h4.x, SACC[0]); SACC[1] = fmaf(p, h4.y, SACC[1]);       \
      SACC[2] = fmaf(p, h4.z, SACC[2]); SACC[3] = fmaf(p, h4.w, SACC[3]);       \
      _Pragma("unroll")                                                         \
      for (int c = 0; c < 4; ++c){                                              \
        const float e1 = (v[c] - mu) * rsg * ((const float*)&gg4)[c]            \
                       + ((const float*)&bb4)[c];                               \
        EACC[c] = fmaf(p, e1, EACC[c]);                                         \
      }                                                                         \
    }                                                                           \
  }

  SUM2_LOOP(posf_end, cf, 0,  h3n4.x, h3n4.y, h3n4.z, h3n4.w, sf, ef)
  SUM2_LOOP(posb_end, cb, 64, h1n4.x, h1n4.y, h1n4.z, h1n4.w, sb, eb)
#undef SUM2_LOOP

  qmerge_(sf); qmerge_(ef); qmerge_(sb); qmerge_(eb);
  if (q == 0){
    float* S = Sall + (size_t)n * 256;
    *(f32x4*)&S[      l16 * 4] = sf;
    *(f32x4*)&S[ 64 + l16 * 4] = ef;
    *(f32x4*)&S[128 + l16 * 4] = sb;
    *(f32x4*)&S[192 + l16 * 4] = eb;
  }
}

// Query-rows-only layer-0 edge update
__global__ __launch_bounds__(256) void k_eu2q(const float* __restrict__ HWp,
    const float2* __restrict__ TEP, const int* __restrict__ ht,
    const int* __restrict__ rt, const int* __restrict__ qi,
    const float* __restrict__ g, const float* __restrict__ be,
    float* __restrict__ e1q, int NQ)
{
  const int w = threadIdx.x >> 6, lane = threadIdx.x & 63;
  const int row = blockIdx.x * 4 + w;
  if (row >= NQ) return;
  const int m = qi[row];
  const int h = ht[2*m], t = ht[2*m+1], r = rt[m];
  const float2 te = TEP[(size_t)r * 64 + lane];
  float v = HWp[(size_t)h*128+lane] + HWp[(size_t)t*128+64+lane] + te.x;
  v = leaky_(v) + te.y;
  e1q[(size_t)row*64+lane] = wln_(v, g[lane], be[lane]);
}

// ---- qi compaction ----
__global__ __launch_bounds__(256) void k_qcount(const int* __restrict__ q,
                                                int* __restrict__ bcnt, int M)
{
  const int j = blockIdx.x * 256 + threadIdx.x;
  const int have = (j < M) && (q[j] != 0);
  unsigned long long bal = __ballot(have);
  if ((threadIdx.x & 63) == 0) atomicAdd(&bcnt[blockIdx.x], (int)__popcll(bal));
}

__global__ __launch_bounds__(256) void k_qemit(const int* __restrict__ q,
    const int* __restrict__ bcnt, int* __restrict__ qi, int M, int NQ)
{
  __shared__ int wb[4];
  const int j = blockIdx.x * 256 + threadIdx.x;
  const int lane = threadIdx.x & 63, w = threadIdx.x >> 6;
  const int have = (j < M) && (q[j] != 0);
  unsigned long long bal = __ballot(have);
  if (lane == 0) wb[w] = (int)__popcll(bal);
  __syncthreads();
  int base = bcnt[blockIdx.x];
  for (int i = 0; i < w; ++i) base += wb[i];
  const int rank = base + (int)__popcll(bal & ((1ull << lane) - 1ull));
  if (have && rank < NQ) qi[rank] = j;
}

// Layer-1 edge update at query rows + feature assembly (E1 from e1q).
__global__ __launch_bounds__(256) void k_feat(
    const float* __restrict__ H, const float* __restrict__ H0,
    const float* __restrict__ e1q, const float* __restrict__ E0t,
    const int* __restrict__ rt, const int* __restrict__ ht, const int* __restrict__ qi,
    const float* __restrict__ W, const float* __restrict__ b,
    const float* __restrict__ g, const float* __restrict__ be,
    float* __restrict__ feat, int NQ)
{
  const int w = threadIdx.x >> 6, d = threadIdx.x & 63;
  const int row = blockIdx.x * 4 + w;
  if (row >= NQ) return;
  const int m = qi[row];
  const int h = ht[2*m], t = ht[2*m+1], r = rt[m];
  const float* seg0 = H   + (size_t)h * 64;
  const float* seg1 = e1q + (size_t)row * 64;
  const float* seg2 = H   + (size_t)t * 64;
  float acc = b[d];
  for (int k4 = 0; k4 < 48; ++k4){
    const int k = k4 * 4;
    const float* A = (k4 < 16) ? seg0 : (k4 < 32) ? seg1 - 64 : seg2 - 128;
    const float4 a = *(const float4*)&A[k];
    acc = fmaf(a.x, W[(k+0)*64+d], fmaf(a.y, W[(k+1)*64+d],
          fmaf(a.z, W[(k+2)*64+d], fmaf(a.w, W[(k+3)*64+d], acc))));
  }
  const float ep = seg1[d];
  const float e2 = wln_(leaky_(acc) + ep, g[d], be[d]);
  float* F = feat + (size_t)row * 384;
  F[      d] = e2;
  F[ 64 + d] = E0t[(size_t)r*64+d];
  F[128 + d] = H [(size_t)h*64+d];
  F[192 + d] = H0[(size_t)h*64+d];
  F[256 + d] = H [(size_t)t*64+d];
  F[320 + d] = H0[(size_t)t*64+d];
}

__global__ __launch_bounds__(256) void k_cls(const float* __restrict__ feat,
    const float* __restrict__ W1, const float* __restrict__ b1,
    const float* __restrict__ W2, const float* __restrict__ b2,
    float* __restrict__ out, int NQ)
{
  const int w = threadIdx.x >> 6, d = threadIdx.x & 63;
  const int row = blockIdx.x * 4 + w;
  if (row >= NQ) return;
  const float* F = feat + (size_t)row * 384;
  float acc = b1[d];
  for (int k4 = 0; k4 < 96; ++k4){
    const int k = k4 * 4;
    const float4 a = *(const float4*)&F[k];
    acc = fmaf(a.x, W1[(k+0)*64+d], fmaf(a.y, W1[(k+1)*64+d],
          fmaf(a.z, W1[(k+2)*64+d], fmaf(a.w, W1[(k+3)*64+d], acc))));
  }
  float hs = leaky_(acc) * W2[d];
  hs = wsum_(hs);
  if (d == 0) out[row] = hs + b2[0];
}

extern "C" void kernel_launch(void* const* d_in, const int* in_sizes, int n_in,
                              void* d_out, int out_size, void* d_ws, size_t ws_size,
                              hipStream_t stream)
{
  const int*   ht    = (const int*)  d_in[0];
  const int*   rt    = (const int*)  d_in[1];
  const float* ef    = (const float*)d_in[2];
  const int*   q     = (const int*)  d_in[3];
  const float* rtab  = (const float*)d_in[4];
  const float* W_ent = (const float*)d_in[5];
  const float* b_ent = (const float*)d_in[6];
  const float* g_ent = (const float*)d_in[7];
  const float* be_ent= (const float*)d_in[8];
  const float* W_ein = (const float*)d_in[9];
  const float* b_ein = (const float*)d_in[10];
  const float* g_e   = (const float*)d_in[11];
  const float* be_e  = (const float*)d_in[12];
  const float* mp_Wf = (const float*)d_in[13];
  const float* mp_bf = (const float*)d_in[14];
  const float* mp_Wb = (const float*)d_in[15];
  const float* mp_bb = (const float*)d_in[16];
  const float* mp_g  = (const float*)d_in[17];
  const float* mp_be = (const float*)d_in[18];
  const float* eu_W  = (const float*)d_in[19];
  const float* eu_b  = (const float*)d_in[20];
  const float* eu_g  = (const float*)d_in[21];
  const float* eu_be = (const float*)d_in[22];
  const float* clsW1 = (const float*)d_in[23];
  const float* clsb1 = (const float*)d_in[24];
  const float* clsW2 = (const float*)d_in[25];
  const float* clsb2 = (const float*)d_in[26];

  const int M    = in_sizes[1];
  const int N    = in_sizes[2] / IN_DIM;
  const int NREL = in_sizes[4] / IN_DIM;
  const int NQ   = out_size;
  const int nb   = (M + 255) / 256;
  const int nbn  = (N + 255) / 256;

  unsigned short* Fhi = (unsigned short*)d_ws;           // NFRAG*512 ushorts
  unsigned short* Flo = Fhi + (size_t)NFRAG * 512;
  float* H0    = (float*)(Flo + (size_t)NFRAG * 512);
  float* H     = H0    + (size_t)N * 64;
  float* HWp   = H     + (size_t)N * 64;                  // [N][128] = HW1|HW3
  float* Sall  = HWp   + (size_t)N * 128;
  float* E0t   = Sall  + (size_t)N * 256;
  float2* TEP  = (float2*)(E0t + (size_t)NREL * 64);      // [NREL][64] of {TE,E0t}
  float* e1q   = (float*)(TEP + (size_t)NREL * 64);
  float* feat  = e1q   + (size_t)NQ * 64;
  int*   cf    = (int*)(feat + (size_t)NQ * 384);
  int*   cb    = cf + N;
  int*   posf  = cb + N;
  int*   posb  = posf + N;
  unsigned* si = (unsigned*)(posb + N);                   // [2M] packed src|rt<<16
  int*   qi    = (int*)(si + 2 * (size_t)M);
  int*   bcnt  = qi + NQ;
  int*   bsumf = bcnt + nb;
  int*   bsumb = bsumf + nbn;

  hipMemsetAsync(cf,   0, (size_t)N  * 4, stream);
  hipMemsetAsync(cb,   0, (size_t)N  * 4, stream);
  hipMemsetAsync(qi,   0, (size_t)NQ * 4, stream);
  hipMemsetAsync(bcnt, 0, (size_t)nb * 4, stream);

  // frag tables + CSR counts/scans
  k_wprep<<<(NFRAG * 64 + 255) / 256, 256, 0, stream>>>(W_ent, mp_Wf, mp_Wb, Fhi, Flo);
  k_cnt<<<(M + 255) / 256, 256, 0, stream>>>(ht, cf, cb, M);
  k_scan1<<<nbn, 256, 0, stream>>>(cf, posf, bsumf, N);
  k_qscan<<<1, 256, 0, stream>>>(bsumf, nbn);
  k_scan3<<<nbn, 256, 0, stream>>>(posf, bsumf, N, 0);
  k_scan1<<<nbn, 256, 0, stream>>>(cb, posb, bsumb, N);
  k_qscan<<<1, 256, 0, stream>>>(bsumb, nbn);
  k_scan3<<<nbn, 256, 0, stream>>>(posb, bsumb, N, M);   // bwd section after M fwd slots

  // FUSED: entity encoder (MFMA blocks) + slot scatter (4 edges/thread)
  const int encBlocks = (N + 63) / 64;
  const int slotBlocks = (M + 1023) / 1024;
  k_encslot<<<encBlocks + slotBlocks, 256, 0, stream>>>(ef, Fhi, Flo,
      b_ent, g_ent, be_ent, H0, H, N, encBlocks, ht, rt, posf, posb, si, M);

  // rel-table encoders + packed eu tables
  k_enc<<<(NREL + 15) / 16, 256, 0, stream>>>(rtab, W_ein, b_ein, g_e, be_e, E0t, nullptr, NREL);
  k_tep<<<(NREL + 15) / 16, 256, 0, stream>>>(E0t, eu_W + 64 * 64, eu_b, TEP, NREL);

  const int sgrid = (N + 3) / 4;
  // ---- layer 0 ----
  k_sum<<<sgrid, 256, 0, stream>>>(H, E0t, si, posf, posb, cf, cb, Sall, N);
  k_hupd2m<<<(N + 63) / 64, 256, 0, stream>>>(H, Sall, cf, cb, Fhi, Flo, FB_L0,
      mp_bf, mp_bb, mp_g, mp_be, N);
  k_xw2<<<(N + 15) / 16, 256, 0, stream>>>(H, eu_W, eu_W + 128 * 64, HWp, N);

  // ---- layer 1 (eu fused into pull-sum; no E1 buffer) ----
  k_sum2<<<sgrid, 256, 0, stream>>>(H, HWp, TEP, si, posf, posb, cf, cb,
      eu_g, eu_be, Sall, N);

  // qi compaction + query-row E1
  k_qcount<<<nb, 256, 0, stream>>>(q, bcnt, M);
  k_qscan<<<1, 256, 0, stream>>>(bcnt, nb);
  k_qemit<<<nb, 256, 0, stream>>>(q, bcnt, qi, M, NQ);
  k_eu2q<<<(NQ + 3) / 4, 256, 0, stream>>>(HWp, TEP, ht, rt, qi,
      eu_g, eu_be, e1q, NQ);

  // layer-1 H update
  k_hupd2m<<<(N + 63) / 64, 256, 0, stream>>>(H, Sall, cf, cb, Fhi, Flo, FB_L1,
      mp_bf + 64, mp_bb + 64, mp_g + 64, mp_be + 64, N);

  // features + classifier
  k_feat<<<(NQ + 3) / 4, 256, 0, stream>>>(H, H0, e1q, E0t, rt, ht, qi,
      eu_W + 192 * 64, eu_b + 64, eu_g + 64, eu_be + 64, feat, NQ);
  k_cls<<<(NQ + 3) / 4, 256, 0, stream>>>(feat, clsW1, clsb1, clsW2, clsb2,
      (float*)d_out, NQ);
}

// Round 18
// 610.239 us; speedup vs baseline: 1.0692x; 1.0692x over previous
//
#include <hip/hip_runtime.h>
#include <hip/hip_bf16.h>
#include <cstdint>

constexpr int IN_DIM = 768;
constexpr int FB_ENT = 0;     // 96 frags: W_ent (768x64)
constexpr int FB_L0  = 96;    // 32 frags: [Wf0;Wb0] stacked (256x64)
constexpr int FB_L1  = 128;   // 32 frags: [Wf1;Wb1] stacked (256x64)
constexpr int FB_EU1 = 160;   // 8 frags: euW rows 0..63   (W1)
constexpr int FB_EU3 = 168;   // 8 frags: euW rows 128..191 (W3)
constexpr int NFRAG  = 176;

typedef __attribute__((ext_vector_type(8))) short bf16x8;
typedef __attribute__((ext_vector_type(4))) float f32x4;

static __device__ __forceinline__ float leaky_(float x){ return x >= 0.0f ? x : 0.01f * x; }

static __device__ __forceinline__ float wsum_(float v){
#pragma unroll
  for (int m = 1; m < 64; m <<= 1) v += __shfl_xor(v, m, 64);
  return v;
}

static __device__ __forceinline__ float wln_(float v, float g, float be){
  float mu  = wsum_(v) * 0.015625f;
  float c   = v - mu;
  float var = wsum_(c * c) * 0.015625f;
  return c * rsqrtf(var + 1e-5f) * g + be;
}

// DPP row_ror<N> add: x += ror_N(x) within each 16-lane row (full-rate VALU).
template<int CTRL>
static __device__ __forceinline__ float dpp_radd(float x){
  const int t = __builtin_amdgcn_update_dpp(0, __float_as_int(x), CTRL, 0xf, 0xf, true);
  return x + __int_as_float(t);
}
static __device__ __forceinline__ float rowsum16_(float x){
  x = dpp_radd<0x121>(x);  // ror:1
  x = dpp_radd<0x122>(x);  // ror:2
  x = dpp_radd<0x124>(x);  // ror:4
  x = dpp_radd<0x128>(x);  // ror:8
  return x;
}

static __device__ __forceinline__ unsigned short f2bf(float x){
  return __bfloat16_as_ushort(__float2bfloat16(x));
}
static __device__ __forceinline__ float bf2f(unsigned short u){
  return __bfloat162float(__ushort_as_bfloat16(u));
}
static __device__ __forceinline__ void split4(const float4 a, ushort4& hi, ushort4& lo){
  hi.x = f2bf(a.x); lo.x = f2bf(a.x - bf2f(hi.x));
  hi.y = f2bf(a.y); lo.y = f2bf(a.y - bf2f(hi.y));
  hi.z = f2bf(a.z); lo.z = f2bf(a.z - bf2f(hi.z));
  hi.w = f2bf(a.w); lo.w = f2bf(a.w - bf2f(hi.w));
}

static __device__ __forceinline__ f32x4 mfma3(bf16x8 ah, bf16x8 al, bf16x8 wh, bf16x8 wl, f32x4 acc){
  acc = __builtin_amdgcn_mfma_f32_16x16x32_bf16(ah, wh, acc, 0, 0, 0);
  acc = __builtin_amdgcn_mfma_f32_16x16x32_bf16(al, wh, acc, 0, 0, 0);
  acc = __builtin_amdgcn_mfma_f32_16x16x32_bf16(ah, wl, acc, 0, 0, 0);
  return acc;
}

// ---------------- weight prep: split-bf16 frag tables ----------------
__global__ __launch_bounds__(256) void k_wprep(
    const float* __restrict__ Went, const float* __restrict__ Wf,
    const float* __restrict__ Wb, const float* __restrict__ euW,
    unsigned short* __restrict__ Fhi, unsigned short* __restrict__ Flo)
{
  const int gt = blockIdx.x * 256 + threadIdx.x;
  if (gt >= NFRAG * 64) return;
  const int fid = gt >> 6, lane = gt & 63;
  int kind, lf;
  if (fid < FB_L0)       { kind = 0; lf = fid; }
  else if (fid < FB_L1)  { kind = 1; lf = fid - FB_L0; }
  else if (fid < FB_EU1) { kind = 2; lf = fid - FB_L1; }
  else if (fid < FB_EU3) { kind = 3; lf = fid - FB_EU1; }
  else                   { kind = 4; lf = fid - FB_EU3; }
  const int kt = lf >> 2, nn = lf & 3;
  const int col = nn * 16 + (lane & 15);
  const int r0  = kt * 32 + (lane >> 4) * 8;
  unsigned short* ph = Fhi + ((size_t)fid << 9) + lane * 8;
  unsigned short* pl = Flo + ((size_t)fid << 9) + lane * 8;
#pragma unroll
  for (int j = 0; j < 8; ++j){
    const int gr = r0 + j;
    const float* rp;
    if (kind == 0)      rp = Went + (size_t)gr * 64;
    else if (kind == 1) rp = (gr < 128) ? Wf + (size_t)gr * 64
                                        : Wb + (size_t)(gr - 128) * 64;
    else if (kind == 2) rp = (gr < 128) ? Wf + (size_t)(128 + gr) * 64
                                        : Wb + (size_t)gr * 64;
    else if (kind == 3) rp = euW + (size_t)gr * 64;          // gr in [0,64)
    else                rp = euW + (size_t)(128 + gr) * 64;  // rows 128..191
    const float v = rp[col];
    const unsigned short h = f2bf(v);
    ph[j] = h;
    pl[j] = f2bf(v - bf2f(h));
  }
}

// ---------------- FUSED: entity encoder (MFMA) + CSR slot scatter ----------------
__global__ __launch_bounds__(256) void k_encslot(const float* __restrict__ X,
    const unsigned short* __restrict__ Fhi, const unsigned short* __restrict__ Flo,
    const float* __restrict__ b, const float* __restrict__ g_,
    const float* __restrict__ be, float* __restrict__ o0, float* __restrict__ o1,
    int nrows, int encBlocks,
    const int* __restrict__ ht, const int* __restrict__ rt,
    int* __restrict__ posf, int* __restrict__ posb,
    unsigned* __restrict__ si, int M)
{
  __shared__ unsigned short Ahi[64 * 128];
  __shared__ unsigned short Alo[64 * 128];
  const int bid = blockIdx.x;
  const int tid = threadIdx.x;

  if (bid >= encBlocks){
    const int m0 = (bid - encBlocks) * 1024;
    int hv[4], tv[4]; unsigned rsh[4]; bool act[4];
#pragma unroll
    for (int j = 0; j < 4; ++j){
      const int m = m0 + j * 256 + tid;
      act[j] = (m < M);
      const int mm = act[j] ? m : 0;
      hv[j] = ht[2*mm]; tv[j] = ht[2*mm+1];
      rsh[j] = ((unsigned)rt[mm]) << 16;
    }
    int sfi[4], sbi[4];
#pragma unroll
    for (int j = 0; j < 4; ++j) if (act[j]) sfi[j] = atomicAdd(&posf[tv[j]], 1);
#pragma unroll
    for (int j = 0; j < 4; ++j) if (act[j]) sbi[j] = atomicAdd(&posb[hv[j]], 1);
#pragma unroll
    for (int j = 0; j < 4; ++j) if (act[j]) si[sfi[j]] = (unsigned)hv[j] | rsh[j];
#pragma unroll
    for (int j = 0; j < 4; ++j) if (act[j]) si[sbi[j]] = (unsigned)tv[j] | rsh[j];
    return;
  }

  const int tile = bid * 64;
  const int w = tid >> 6, lane = tid & 63, g = lane >> 4, lr = lane & 15;
  const int rowb = w * 16;

  f32x4 acc[4];
#pragma unroll
  for (int n = 0; n < 4; ++n){
    const float bv = b[n * 16 + lr];
    acc[n] = (f32x4){bv, bv, bv, bv};
  }

  for (int ch = 0; ch < 6; ++ch){
    __syncthreads();
#pragma unroll
    for (int i = 0; i < 8; ++i){
      const int idx = tid + 256 * i;
      const int row = idx >> 5, c = idx & 31;
      int gr = tile + row; if (gr >= nrows) gr = nrows - 1;
      const float4 a = *(const float4*)&X[(size_t)gr * IN_DIM + ch * 128 + c * 4];
      ushort4 hi, lo; split4(a, hi, lo);
      const int ad = (row * 256 + c * 8) ^ ((row & 7) << 4);
      *(ushort4*)((char*)Ahi + ad) = hi;
      *(ushort4*)((char*)Alo + ad) = lo;
    }
    __syncthreads();

    bf16x8 Ah[4], Al[4];
#pragma unroll
    for (int kt = 0; kt < 4; ++kt){
      const int row = rowb + lr;
      const int ad = (row * 256 + kt * 64 + g * 16) ^ ((row & 7) << 4);
      Ah[kt] = *(const bf16x8*)((const char*)Ahi + ad);
      Al[kt] = *(const bf16x8*)((const char*)Alo + ad);
    }
    const int fb = ch * 16;
#pragma unroll
    for (int n = 0; n < 4; ++n)
#pragma unroll
      for (int kt = 0; kt < 4; ++kt){
        const size_t fo = (((size_t)(fb + kt * 4 + n)) << 9) + lane * 8;
        acc[n] = mfma3(Ah[kt], Al[kt], *(const bf16x8*)(Fhi + fo), *(const bf16x8*)(Flo + fo), acc[n]);
      }
  }

#pragma unroll
  for (int reg = 0; reg < 4; ++reg){
    const int lrow = rowb + g * 4 + reg;
    float v[4];
#pragma unroll
    for (int n = 0; n < 4; ++n) v[n] = leaky_(acc[n][reg]);
    float s = v[0] + v[1] + v[2] + v[3];
#pragma unroll
    for (int msk = 1; msk < 16; msk <<= 1) s += __shfl_xor(s, msk, 64);
    const float mu = s * 0.015625f;
    float q = 0.f;
#pragma unroll
    for (int n = 0; n < 4; ++n){ v[n] -= mu; q += v[n] * v[n]; }
#pragma unroll
    for (int msk = 1; msk < 16; msk <<= 1) q += __shfl_xor(q, msk, 64);
    const float rs = rsqrtf(q * 0.015625f + 1e-5f);
    const int r = tile + lrow;
    if (r < nrows){
#pragma unroll
      for (int n = 0; n < 4; ++n){
        const int col = n * 16 + lr;
        const float o = v[n] * rs * g_[col] + be[col];
        o0[(size_t)r * 64 + col] = o;
        o1[(size_t)r * 64 + col] = o;
      }
    }
  }
}

// ---------------- layer-1 H update (MFMA), unchanged ----------------
__global__ __launch_bounds__(256) void k_hupd2m(float* __restrict__ H,
    const float* __restrict__ Sall,
    const int* __restrict__ cf, const int* __restrict__ cb,
    const unsigned short* __restrict__ Fhi, const unsigned short* __restrict__ Flo, int fb,
    const float* __restrict__ bf, const float* __restrict__ bb,
    const float* __restrict__ g_, const float* __restrict__ be, int N)
{
  __shared__ unsigned short Ahi[64 * 256];
  __shared__ unsigned short Alo[64 * 256];
  const int tile = blockIdx.x * 64, tid = threadIdx.x;
#pragma unroll
  for (int i = 0; i < 16; ++i){
    const int idx = tid + 256 * i;
    const int row = idx >> 6, c = idx & 63;
    int gr = tile + row; if (gr >= N) gr = N - 1;
    const float4 a = *(const float4*)&Sall[(size_t)gr * 256 + c * 4];
    ushort4 hi, lo; split4(a, hi, lo);
    const int ad = (row * 512 + c * 8) ^ ((row & 7) << 4);
    *(ushort4*)((char*)Ahi + ad) = hi;
    *(ushort4*)((char*)Alo + ad) = lo;
  }
  __syncthreads();

  const int w = tid >> 6, lane = tid & 63, g = lane >> 4, lr = lane & 15;
  const int rowb = w * 16;
  bf16x8 Ah[8], Al[8];
#pragma unroll
  for (int kt = 0; kt < 8; ++kt){
    const int row = rowb + lr;
    const int ad = (row * 512 + kt * 64 + g * 16) ^ ((row & 7) << 4);
    Ah[kt] = *(const bf16x8*)((const char*)Ahi + ad);
    Al[kt] = *(const bf16x8*)((const char*)Alo + ad);
  }

  int cfv[4], cbv[4];
#pragma unroll
  for (int reg = 0; reg < 4; ++reg){
    int r = tile + rowb + g * 4 + reg; if (r >= N) r = N - 1;
    cfv[reg] = cf[r]; cbv[reg] = cb[r];
  }
  f32x4 acc[4];
#pragma unroll
  for (int n = 0; n < 4; ++n){
    const float bfc = bf[n * 16 + lr], bbc = bb[n * 16 + lr];
#pragma unroll
    for (int reg = 0; reg < 4; ++reg)
      acc[n][reg] = (float)cfv[reg] * bfc + (float)cbv[reg] * bbc;
  }
#pragma unroll
  for (int n = 0; n < 4; ++n)
#pragma unroll
    for (int kt = 0; kt < 8; ++kt){
      const size_t fo = (((size_t)(fb + kt * 4 + n)) << 9) + lane * 8;
      acc[n] = mfma3(Ah[kt], Al[kt], *(const bf16x8*)(Fhi + fo), *(const bf16x8*)(Flo + fo), acc[n]);
    }

#pragma unroll
  for (int reg = 0; reg < 4; ++reg){
    const int lrow = rowb + g * 4 + reg;
    const int r = tile + lrow;
    const int rr = (r < N) ? r : N - 1;
    const float c = (float)(cfv[reg] + cbv[reg]);
    float v[4];
#pragma unroll
    for (int n = 0; n < 4; ++n)
      v[n] = leaky_(acc[n][reg] / c) + H[(size_t)rr * 64 + n * 16 + lr];
    float s = v[0] + v[1] + v[2] + v[3];
#pragma unroll
    for (int msk = 1; msk < 16; msk <<= 1) s += __shfl_xor(s, msk, 64);
    const float mu = s * 0.015625f;
    float q = 0.f;
#pragma unroll
    for (int n = 0; n < 4; ++n){ v[n] -= mu; q += v[n] * v[n]; }
#pragma unroll
    for (int msk = 1; msk < 16; msk <<= 1) q += __shfl_xor(q, msk, 64);
    const float rs = rsqrtf(q * 0.015625f + 1e-5f);
    if (r < N){
#pragma unroll
      for (int n = 0; n < 4; ++n){
        const int col = n * 16 + lr;
        H[(size_t)r * 64 + col] = v[n] * rs * g_[col] + be[col];
      }
    }
  }
}

// ---------------- layer-0 H update + FUSED HWp = [H@euW1 | H@euW3] ----------------
__global__ __launch_bounds__(256) void k_hupd2mx(float* __restrict__ H,
    const float* __restrict__ Sall,
    const int* __restrict__ cf, const int* __restrict__ cb,
    const unsigned short* __restrict__ Fhi, const unsigned short* __restrict__ Flo,
    const float* __restrict__ bf, const float* __restrict__ bb,
    const float* __restrict__ g_, const float* __restrict__ be,
    float* __restrict__ HWp, int N)
{
  __shared__ unsigned short Ahi[64 * 256];
  __shared__ unsigned short Alo[64 * 256];
  const int tile = blockIdx.x * 64, tid = threadIdx.x;
#pragma unroll
  for (int i = 0; i < 16; ++i){
    const int idx = tid + 256 * i;
    const int row = idx >> 6, c = idx & 63;
    int gr = tile + row; if (gr >= N) gr = N - 1;
    const float4 a = *(const float4*)&Sall[(size_t)gr * 256 + c * 4];
    ushort4 hi, lo; split4(a, hi, lo);
    const int ad = (row * 512 + c * 8) ^ ((row & 7) << 4);
    *(ushort4*)((char*)Ahi + ad) = hi;
    *(ushort4*)((char*)Alo + ad) = lo;
  }
  __syncthreads();

  const int w = tid >> 6, lane = tid & 63, g = lane >> 4, lr = lane & 15;
  const int rowb = w * 16;
  bf16x8 Ah[8], Al[8];
#pragma unroll
  for (int kt = 0; kt < 8; ++kt){
    const int row = rowb + lr;
    const int ad = (row * 512 + kt * 64 + g * 16) ^ ((row & 7) << 4);
    Ah[kt] = *(const bf16x8*)((const char*)Ahi + ad);
    Al[kt] = *(const bf16x8*)((const char*)Alo + ad);
  }

  int cfv[4], cbv[4];
#pragma unroll
  for (int reg = 0; reg < 4; ++reg){
    int r = tile + rowb + g * 4 + reg; if (r >= N) r = N - 1;
    cfv[reg] = cf[r]; cbv[reg] = cb[r];
  }
  f32x4 acc[4];
#pragma unroll
  for (int n = 0; n < 4; ++n){
    const float bfc = bf[n * 16 + lr], bbc = bb[n * 16 + lr];
#pragma unroll
    for (int reg = 0; reg < 4; ++reg)
      acc[n][reg] = (float)cfv[reg] * bfc + (float)cbv[reg] * bbc;
  }
#pragma unroll
  for (int n = 0; n < 4; ++n)
#pragma unroll
    for (int kt = 0; kt < 8; ++kt){
      const size_t fo = (((size_t)(FB_L0 + kt * 4 + n)) << 9) + lane * 8;
      acc[n] = mfma3(Ah[kt], Al[kt], *(const bf16x8*)(Fhi + fo), *(const bf16x8*)(Flo + fo), acc[n]);
    }

  // all LDS frag reads are done; fence before reusing LDS for the fresh-H tile
  __syncthreads();

#pragma unroll
  for (int reg = 0; reg < 4; ++reg){
    const int lrow = rowb + g * 4 + reg;
    const int r = tile + lrow;
    const int rr = (r < N) ? r : N - 1;
    const float c = (float)(cfv[reg] + cbv[reg]);
    float v[4];
#pragma unroll
    for (int n = 0; n < 4; ++n)
      v[n] = leaky_(acc[n][reg] / c) + H[(size_t)rr * 64 + n * 16 + lr];
    float s = v[0] + v[1] + v[2] + v[3];
#pragma unroll
    for (int msk = 1; msk < 16; msk <<= 1) s += __shfl_xor(s, msk, 64);
    const float mu = s * 0.015625f;
    float q = 0.f;
#pragma unroll
    for (int n = 0; n < 4; ++n){ v[n] -= mu; q += v[n] * v[n]; }
#pragma unroll
    for (int msk = 1; msk < 16; msk <<= 1) q += __shfl_xor(q, msk, 64);
    const float rs = rsqrtf(q * 0.015625f + 1e-5f);
#pragma unroll
    for (int n = 0; n < 4; ++n){
      const int col = n * 16 + lr;
      const float o = v[n] * rs * g_[col] + be[col];
      if (r < N) H[(size_t)r * 64 + col] = o;
      // stash fresh H (split bf16) into [64][64] LDS tile, 128B rows, swizzled
      const int ad2 = (lrow * 128 + col * 2) ^ ((lrow & 7) << 4);
      const unsigned short hh = f2bf(o);
      *(unsigned short*)((char*)Ahi + ad2) = hh;
      *(unsigned short*)((char*)Alo + ad2) = f2bf(o - bf2f(hh));
    }
  }
  __syncthreads();

  // second matmul: HWp[r][0:64] = H@euW1 ; HWp[r][64:128] = H@euW3 (K=64)
  bf16x8 Bh[2], Bl[2];
#pragma unroll
  for (int kt = 0; kt < 2; ++kt){
    const int row = rowb + lr;
    const int ad = (row * 128 + kt * 64 + g * 16) ^ ((row & 7) << 4);
    Bh[kt] = *(const bf16x8*)((const char*)Ahi + ad);
    Bl[kt] = *(const bf16x8*)((const char*)Alo + ad);
  }
  f32x4 a1[4], a3[4];
#pragma unroll
  for (int n = 0; n < 4; ++n){ a1[n] = (f32x4){0,0,0,0}; a3[n] = (f32x4){0,0,0,0}; }
#pragma unroll
  for (int n = 0; n < 4; ++n)
#pragma unroll
    for (int kt = 0; kt < 2; ++kt){
      const size_t f1 = (((size_t)(FB_EU1 + kt * 4 + n)) << 9) + lane * 8;
      const size_t f3 = (((size_t)(FB_EU3 + kt * 4 + n)) << 9) + lane * 8;
      a1[n] = mfma3(Bh[kt], Bl[kt], *(const bf16x8*)(Fhi + f1), *(const bf16x8*)(Flo + f1), a1[n]);
      a3[n] = mfma3(Bh[kt], Bl[kt], *(const bf16x8*)(Fhi + f3), *(const bf16x8*)(Flo + f3), a3[n]);
    }
#pragma unroll
  for (int reg = 0; reg < 4; ++reg){
    const int r = tile + rowb + g * 4 + reg;
    if (r < N){
#pragma unroll
      for (int n = 0; n < 4; ++n){
        const int col = n * 16 + lr;
        HWp[(size_t)r * 128 + col]      = a1[n][reg];
        HWp[(size_t)r * 128 + 64 + col] = a3[n][reg];
      }
    }
  }
}

// ---------------- f32 encoder (rel table, 500 rows) ----------------
__global__ __launch_bounds__(256) void k_enc(const float* __restrict__ X,
    const float* __restrict__ W, const float* __restrict__ b,
    const float* __restrict__ g, const float* __restrict__ be,
    float* __restrict__ o0, float* __restrict__ o1, int nrows)
{
  const int w = threadIdx.x >> 6, d = threadIdx.x & 63;
  const int rbase = blockIdx.x * 16 + w * 4;
  int rows[4];
#pragma unroll
  for (int j = 0; j < 4; ++j){ int r = rbase + j; rows[j] = r < nrows ? r : nrows - 1; }
  float acc[4] = {0.f, 0.f, 0.f, 0.f};
  for (int k4 = 0; k4 < IN_DIM / 4; ++k4){
    const int k = k4 * 4;
    const float w0 = W[(k+0)*64+d], w1 = W[(k+1)*64+d];
    const float w2 = W[(k+2)*64+d], w3 = W[(k+3)*64+d];
#pragma unroll
    for (int j = 0; j < 4; ++j){
      const float4 a = *(const float4*)&X[(size_t)rows[j] * IN_DIM + k];
      acc[j] = fmaf(a.x, w0, fmaf(a.y, w1, fmaf(a.z, w2, fmaf(a.w, w3, acc[j]))));
    }
  }
#pragma unroll
  for (int j = 0; j < 4; ++j){
    const int r = rbase + j;
    if (r < nrows){
      float v = wln_(leaky_(acc[j] + b[d]), g[d], be[d]);
      o0[(size_t)r*64+d] = v;
      if (o1) o1[(size_t)r*64+d] = v;
    }
  }
}

// TE pack: TEP[r*64+d] = { (E0t@euW2+eu_b)[r][d], E0t[r][d] }
__global__ __launch_bounds__(256) void k_tep(const float* __restrict__ E0t,
    const float* __restrict__ W, const float* __restrict__ bias,
    float2* __restrict__ TEP, int nrows)
{
  const int w = threadIdx.x >> 6, d = threadIdx.x & 63;
  const int rbase = blockIdx.x * 16 + w * 4;
  int rows[4];
#pragma unroll
  for (int j = 0; j < 4; ++j){ int r = rbase + j; rows[j] = r < nrows ? r : nrows - 1; }
  const float b0 = bias[d];
  float acc[4] = {b0, b0, b0, b0};
  for (int k4 = 0; k4 < 16; ++k4){
    const int k = k4 * 4;
    const float w0 = W[(k+0)*64+d], w1 = W[(k+1)*64+d];
    const float w2 = W[(k+2)*64+d], w3 = W[(k+3)*64+d];
#pragma unroll
    for (int j = 0; j < 4; ++j){
      const float4 a = *(const float4*)&E0t[(size_t)rows[j] * 64 + k];
      acc[j] = fmaf(a.x, w0, fmaf(a.y, w1, fmaf(a.z, w2, fmaf(a.w, w3, acc[j]))));
    }
  }
#pragma unroll
  for (int j = 0; j < 4; ++j){
    const int r = rbase + j;
    if (r < nrows) TEP[(size_t)r * 64 + d] = make_float2(acc[j], E0t[(size_t)r * 64 + d]);
  }
}

// Degree counts
__global__ __launch_bounds__(256) void k_cnt(const int* __restrict__ ht,
    int* __restrict__ cf, int* __restrict__ cb, int M)
{
  int m = blockIdx.x * 256 + threadIdx.x;
  if (m < M){
    atomicAdd(&cf[ht[2*m+1]], 1);
    atomicAdd(&cb[ht[2*m+0]], 1);
  }
}

// ---- parallel exclusive scan over a single count array ----
__global__ __launch_bounds__(256) void k_scan1(const int* __restrict__ c,
    int* __restrict__ pos, int* __restrict__ bsum, int N)
{
  __shared__ int ws[4];
  const int tid = threadIdx.x, lane = tid & 63, w = tid >> 6;
  const int i = blockIdx.x * 256 + tid;
  const int v = (i < N) ? c[i] : 0;
  int inc = v;
#pragma unroll
  for (int off = 1; off < 64; off <<= 1){
    int t = __shfl_up(inc, off, 64);
    if (lane >= off) inc += t;
  }
  if (lane == 63) ws[w] = inc;
  __syncthreads();
  int wbase = 0;
  for (int j = 0; j < w; ++j) wbase += ws[j];
  if (i < N) pos[i] = wbase + inc - v;
  if (tid == 255) bsum[blockIdx.x] = wbase + inc;
}

__global__ __launch_bounds__(256) void k_scan3(int* __restrict__ pos,
    const int* __restrict__ bsum, int N, int offset)
{
  const int i = blockIdx.x * 256 + threadIdx.x;
  if (i < N) pos[i] += bsum[blockIdx.x] + offset;
}

// Generic small single-block exclusive scan (in place).
__global__ __launch_bounds__(256) void k_qscan(int* __restrict__ bcnt, int nb)
{
  __shared__ int ws[4];
  const int tid = threadIdx.x, lane = tid & 63, w = tid >> 6;
  const int chunk = (nb + 255) / 256;
  int s = 0;
  for (int i = 0; i < chunk; ++i){ int idx = tid * chunk + i; if (idx < nb) s += bcnt[idx]; }
  int v = s;
#pragma unroll
  for (int off = 1; off < 64; off <<= 1){ int t = __shfl_up(v, off, 64); if (lane >= off) v += t; }
  if (lane == 63) ws[w] = v;
  __syncthreads();
  int wbase = 0;
  for (int i = 0; i < w; ++i) wbase += ws[i];
  int run = wbase + v - s;
  for (int i = 0; i < chunk; ++i){
    int idx = tid * chunk + i;
    if (idx < nb){ int t = bcnt[idx]; bcnt[idx] = run; run += t; }
  }
}

// Cross-quarter merge (masks 16, 32) for a f32x4 accumulator.
static __device__ __forceinline__ void qmerge_(f32x4& a){
#pragma unroll
  for (int c = 0; c < 4; ++c){
    float x = a[c];
    x += __shfl_xor(x, 16, 64);
    x += __shfl_xor(x, 32, 64);
    a[c] = x;
  }
}

// Layer-0 CSR pull-sum, quarter-wave, split fwd/bwd loops.
__global__ __launch_bounds__(256) void k_sum(const float* __restrict__ H,
    const float* __restrict__ E, const unsigned* __restrict__ si,
    const int* __restrict__ posf_end, const int* __restrict__ posb_end,
    const int* __restrict__ cf, const int* __restrict__ cb,
    float* __restrict__ Sall, int N)
{
  const int w = threadIdx.x >> 6, lane = threadIdx.x & 63;
  const int n = blockIdx.x * 4 + w;
  if (n >= N) return;
  const int q = lane >> 4, l16 = lane & 15;
  f32x4 sf = {0,0,0,0}, ef = {0,0,0,0}, sb = {0,0,0,0}, eb = {0,0,0,0};
  {
    const int end = posf_end[n], start = end - cf[n];
#pragma unroll 2
    for (int i0 = start; i0 < end; i0 += 4){
      int i = i0 + q;
      const bool act = (i < end); if (!act) i = end - 1;
      const unsigned sv = si[i];
      const int src = (int)(sv & 0xffffu), r = (int)(sv >> 16);
      const float4 h4 = *(const float4*)&H[(size_t)src * 64 + l16 * 4];
      const float4 e4 = *(const float4*)&E[(size_t)r * 64 + l16 * 4];
      const float p = act ? 1.f : 0.f;
      sf[0] = fmaf(p, h4.x, sf[0]); sf[1] = fmaf(p, h4.y, sf[1]);
      sf[2] = fmaf(p, h4.z, sf[2]); sf[3] = fmaf(p, h4.w, sf[3]);
      ef[0] = fmaf(p, e4.x, ef[0]); ef[1] = fmaf(p, e4.y, ef[1]);
      ef[2] = fmaf(p, e4.z, ef[2]); ef[3] = fmaf(p, e4.w, ef[3]);
    }
  }
  {
    const int end = posb_end[n], start = end - cb[n];
#pragma unroll 2
    for (int i0 = start; i0 < end; i0 += 4){
      int i = i0 + q;
      const bool act = (i < end); if (!act) i = end - 1;
      const unsigned sv = si[i];
      const int src = (int)(sv & 0xffffu), r = (int)(sv >> 16);
      const float4 h4 = *(const float4*)&H[(size_t)src * 64 + l16 * 4];
      const float4 e4 = *(const float4*)&E[(size_t)r * 64 + l16 * 4];
      const float p = act ? 1.f : 0.f;
      sb[0] = fmaf(p, h4.x, sb[0]); sb[1] = fmaf(p, h4.y, sb[1]);
      sb[2] = fmaf(p, h4.z, sb[2]); sb[3] = fmaf(p, h4.w, sb[3]);
      eb[0] = fmaf(p, e4.x, eb[0]); eb[1] = fmaf(p, e4.y, eb[1]);
      eb[2] = fmaf(p, e4.z, eb[2]); eb[3] = fmaf(p, e4.w, eb[3]);
    }
  }
  qmerge_(sf); qmerge_(ef); qmerge_(sb); qmerge_(eb);
  if (q == 0){
    float* S = Sall + (size_t)n * 256;
    *(f32x4*)&S[      l16 * 4] = sf;
    *(f32x4*)&S[ 64 + l16 * 4] = ef;
    *(f32x4*)&S[128 + l16 * 4] = sb;
    *(f32x4*)&S[192 + l16 * 4] = eb;
  }
}

// Layer-1 CSR pull-sum with fused edge update, quarter-wave, split loops.
__global__ __launch_bounds__(256) void k_sum2(const float* __restrict__ H,
    const float* __restrict__ HWp, const float2* __restrict__ TEP,
    const unsigned* __restrict__ si,
    const int* __restrict__ posf_end, const int* __restrict__ posb_end,
    const int* __restrict__ cf, const int* __restrict__ cb,
    const float* __restrict__ g0, const float* __restrict__ be0,
    float* __restrict__ Sall, int N)
{
  const int w = threadIdx.x >> 6, lane = threadIdx.x & 63;
  const int n = blockIdx.x * 4 + w;
  if (n >= N) return;
  const int q = lane >> 4, l16 = lane & 15;
  const float4 gg4  = *(const float4*)&g0 [l16 * 4];
  const float4 bb4  = *(const float4*)&be0[l16 * 4];
  const float4 h1n4 = *(const float4*)&HWp[(size_t)n * 128 +      l16 * 4];
  const float4 h3n4 = *(const float4*)&HWp[(size_t)n * 128 + 64 + l16 * 4];
  f32x4 sf = {0,0,0,0}, ef = {0,0,0,0}, sb = {0,0,0,0}, eb = {0,0,0,0};

#define SUM2_LOOP(POS_END, CNT, OTH_OFF, N0, N1, N2, N3, SACC, EACC)            \
  {                                                                             \
    const int end = POS_END[n], start = end - CNT[n];                           \
    _Pragma("unroll 2")                                                         \
    for (int i0 = start; i0 < end; i0 += 4){                                    \
      int i = i0 + q;                                                           \
      const bool act = (i < end); if (!act) i = end - 1;                        \
      const unsigned sv = si[i];                                                \
      const int src = (int)(sv & 0xffffu), rr_ = (int)(sv >> 16);               \
      const float4 h4 = *(const float4*)&H[(size_t)src * 64 + l16 * 4];         \
      const float4 o4 = *(const float4*)&HWp[(size_t)src * 128 + OTH_OFF + l16 * 4]; \
      const float* tp = (const float*)&TEP[(size_t)rr_ * 64 + l16 * 4];         \
      const float4 t0 = *(const float4*)&tp[0];                                 \
      const float4 t1 = *(const float4*)&tp[4];                                 \
      float v[4];                                                               \
      v[0] = leaky_(o4.x + N0 + t0.x) + t0.y;                                   \
      v[1] = leaky_(o4.y + N1 + t0.z) + t0.w;                                   \
      v[2] = leaky_(o4.z + N2 + t1.x) + t1.y;                                   \
      v[3] = leaky_(o4.w + N3 + t1.z) + t1.w;                                   \
      float s  = (v[0] + v[1]) + (v[2] + v[3]);                                 \
      float qq = fmaf(v[0], v[0], v[1] * v[1]) + fmaf(v[2], v[2], v[3] * v[3]); \
      s  = rowsum16_(s);                                                        \
      qq = rowsum16_(qq);                                                       \
      const float mu  = s * 0.015625f;                                          \
      const float var = fmaxf(qq * 0.015625f - mu * mu, 0.f);                   \
      const float rsg = rsqrtf(var + 1e-5f);                                    \
      const float p = act ? 1.f : 0.f;                                          \
      SACC[0] = fmaf(p, h4.x, SACC[0]); SACC[1] = fmaf(p, h4.y, SACC[1]);       \
      SACC[2] = fmaf(p, h4.z, SACC[2]); SACC[3] = fmaf(p, h4.w, SACC[3]);       \
      _Pragma("unroll")                                                         \
      for (int c = 0; c < 4; ++c){                                              \
        const float e1 = (v[c] - mu) * rsg * ((const float*)&gg4)[c]            \
                       + ((const float*)&bb4)[c];                               \
        EACC[c] = fmaf(p, e1, EACC[c]);                                         \
      }                                                                         \
    }                                                                           \
  }

  SUM2_LOOP(posf_end, cf, 0,  h3n4.x, h3n4.y, h3n4.z, h3n4.w, sf, ef)
  SUM2_LOOP(posb_end, cb, 64, h1n4.x, h1n4.y, h1n4.z, h1n4.w, sb, eb)
#undef SUM2_LOOP

  qmerge_(sf); qmerge_(ef); qmerge_(sb); qmerge_(eb);
  if (q == 0){
    float* S = Sall + (size_t)n * 256;
    *(f32x4*)&S[      l16 * 4] = sf;
    *(f32x4*)&S[ 64 + l16 * 4] = ef;
    *(f32x4*)&S[128 + l16 * 4] = sb;
    *(f32x4*)&S[192 + l16 * 4] = eb;
  }
}

// Query-rows-only layer-0 edge update
__global__ __launch_bounds__(256) void k_eu2q(const float* __restrict__ HWp,
    const float2* __restrict__ TEP, const int* __restrict__ ht,
    const int* __restrict__ rt, const int* __restrict__ qi,
    const float* __restrict__ g, const float* __restrict__ be,
    float* __restrict__ e1q, int NQ)
{
  const int w = threadIdx.x >> 6, lane = threadIdx.x & 63;
  const int row = blockIdx.x * 4 + w;
  if (row >= NQ) return;
  const int m = qi[row];
  const int h = ht[2*m], t = ht[2*m+1], r = rt[m];
  const float2 te = TEP[(size_t)r * 64 + lane];
  float v = HWp[(size_t)h*128+lane] + HWp[(size_t)t*128+64+lane] + te.x;
  v = leaky_(v) + te.y;
  e1q[(size_t)row*64+lane] = wln_(v, g[lane], be[lane]);
}

// ---- qi compaction ----
__global__ __launch_bounds__(256) void k_qcount(const int* __restrict__ q,
                                                int* __restrict__ bcnt, int M)
{
  const int j = blockIdx.x * 256 + threadIdx.x;
  const int have = (j < M) && (q[j] != 0);
  unsigned long long bal = __ballot(have);
  if ((threadIdx.x & 63) == 0) atomicAdd(&bcnt[blockIdx.x], (int)__popcll(bal));
}

__global__ __launch_bounds__(256) void k_qemit(const int* __restrict__ q,
    const int* __restrict__ bcnt, int* __restrict__ qi, int M, int NQ)
{
  __shared__ int wb[4];
  const int j = blockIdx.x * 256 + threadIdx.x;
  const int lane = threadIdx.x & 63, w = threadIdx.x >> 6;
  const int have = (j < M) && (q[j] != 0);
  unsigned long long bal = __ballot(have);
  if (lane == 0) wb[w] = (int)__popcll(bal);
  __syncthreads();
  int base = bcnt[blockIdx.x];
  for (int i = 0; i < w; ++i) base += wb[i];
  const int rank = base + (int)__popcll(bal & ((1ull << lane) - 1ull));
  if (have && rank < NQ) qi[rank] = j;
}

// Layer-1 edge update at query rows + feature assembly (E1 from e1q).
__global__ __launch_bounds__(256) void k_feat(
    const float* __restrict__ H, const float* __restrict__ H0,
    const float* __restrict__ e1q, const float* __restrict__ E0t,
    const int* __restrict__ rt, const int* __restrict__ ht, const int* __restrict__ qi,
    const float* __restrict__ W, const float* __restrict__ b,
    const float* __restrict__ g, const float* __restrict__ be,
    float* __restrict__ feat, int NQ)
{
  const int w = threadIdx.x >> 6, d = threadIdx.x & 63;
  const int row = blockIdx.x * 4 + w;
  if (row >= NQ) return;
  const int m = qi[row];
  const int h = ht[2*m], t = ht[2*m+1], r = rt[m];
  const float* seg0 = H   + (size_t)h * 64;
  const float* seg1 = e1q + (size_t)row * 64;
  const float* seg2 = H   + (size_t)t * 64;
  float acc = b[d];
  for (int k4 = 0; k4 < 48; ++k4){
    const int k = k4 * 4;
    const float* A = (k4 < 16) ? seg0 : (k4 < 32) ? seg1 - 64 : seg2 - 128;
    const float4 a = *(const float4*)&A[k];
    acc = fmaf(a.x, W[(k+0)*64+d], fmaf(a.y, W[(k+1)*64+d],
          fmaf(a.z, W[(k+2)*64+d], fmaf(a.w, W[(k+3)*64+d], acc))));
  }
  const float ep = seg1[d];
  const float e2 = wln_(leaky_(acc) + ep, g[d], be[d]);
  float* F = feat + (size_t)row * 384;
  F[      d] = e2;
  F[ 64 + d] = E0t[(size_t)r*64+d];
  F[128 + d] = H [(size_t)h*64+d];
  F[192 + d] = H0[(size_t)h*64+d];
  F[256 + d] = H [(size_t)t*64+d];
  F[320 + d] = H0[(size_t)t*64+d];
}

__global__ __launch_bounds__(256) void k_cls(const float* __restrict__ feat,
    const float* __restrict__ W1, const float* __restrict__ b1,
    const float* __restrict__ W2, const float* __restrict__ b2,
    float* __restrict__ out, int NQ)
{
  const int w = threadIdx.x >> 6, d = threadIdx.x & 63;
  const int row = blockIdx.x * 4 + w;
  if (row >= NQ) return;
  const float* F = feat + (size_t)row * 384;
  float acc = b1[d];
  for (int k4 = 0; k4 < 96; ++k4){
    const int k = k4 * 4;
    const float4 a = *(const float4*)&F[k];
    acc = fmaf(a.x, W1[(k+0)*64+d], fmaf(a.y, W1[(k+1)*64+d],
          fmaf(a.z, W1[(k+2)*64+d], fmaf(a.w, W1[(k+3)*64+d], acc))));
  }
  float hs = leaky_(acc) * W2[d];
  hs = wsum_(hs);
  if (d == 0) out[row] = hs + b2[0];
}

extern "C" void kernel_launch(void* const* d_in, const int* in_sizes, int n_in,
                              void* d_out, int out_size, void* d_ws, size_t ws_size,
                              hipStream_t stream)
{
  const int*   ht    = (const int*)  d_in[0];
  const int*   rt    = (const int*)  d_in[1];
  const float* ef    = (const float*)d_in[2];
  const int*   q     = (const int*)  d_in[3];
  const float* rtab  = (const float*)d_in[4];
  const float* W_ent = (const float*)d_in[5];
  const float* b_ent = (const float*)d_in[6];
  const float* g_ent = (const float*)d_in[7];
  const float* be_ent= (const float*)d_in[8];
  const float* W_ein = (const float*)d_in[9];
  const float* b_ein = (const float*)d_in[10];
  const float* g_e   = (const float*)d_in[11];
  const float* be_e  = (const float*)d_in[12];
  const float* mp_Wf = (const float*)d_in[13];
  const float* mp_bf = (const float*)d_in[14];
  const float* mp_Wb = (const float*)d_in[15];
  const float* mp_bb = (const float*)d_in[16];
  const float* mp_g  = (const float*)d_in[17];
  const float* mp_be = (const float*)d_in[18];
  const float* eu_W  = (const float*)d_in[19];
  const float* eu_b  = (const float*)d_in[20];
  const float* eu_g  = (const float*)d_in[21];
  const float* eu_be = (const float*)d_in[22];
  const float* clsW1 = (const float*)d_in[23];
  const float* clsb1 = (const float*)d_in[24];
  const float* clsW2 = (const float*)d_in[25];
  const float* clsb2 = (const float*)d_in[26];

  const int M    = in_sizes[1];
  const int N    = in_sizes[2] / IN_DIM;
  const int NREL = in_sizes[4] / IN_DIM;
  const int NQ   = out_size;
  const int nb   = (M + 255) / 256;
  const int nbn  = (N + 255) / 256;

  unsigned short* Fhi = (unsigned short*)d_ws;           // NFRAG*512 ushorts
  unsigned short* Flo = Fhi + (size_t)NFRAG * 512;
  float* H0    = (float*)(Flo + (size_t)NFRAG * 512);
  float* H     = H0    + (size_t)N * 64;
  float* HWp   = H     + (size_t)N * 64;                  // [N][128] = HW1|HW3
  float* Sall  = HWp   + (size_t)N * 128;
  float* E0t   = Sall  + (size_t)N * 256;
  float2* TEP  = (float2*)(E0t + (size_t)NREL * 64);      // [NREL][64] of {TE,E0t}
  float* e1q   = (float*)(TEP + (size_t)NREL * 64);
  float* feat  = e1q   + (size_t)NQ * 64;
  int*   cf    = (int*)(feat + (size_t)NQ * 384);
  int*   cb    = cf + N;
  int*   posf  = cb + N;
  int*   posb  = posf + N;
  unsigned* si = (unsigned*)(posb + N);                   // [2M] packed src|rt<<16
  int*   qi    = (int*)(si + 2 * (size_t)M);
  int*   bcnt  = qi + NQ;
  int*   bsumf = bcnt + nb;
  int*   bsumb = bsumf + nbn;

  hipMemsetAsync(cf,   0, (size_t)N  * 4, stream);
  hipMemsetAsync(cb,   0, (size_t)N  * 4, stream);
  hipMemsetAsync(qi,   0, (size_t)NQ * 4, stream);
  hipMemsetAsync(bcnt, 0, (size_t)nb * 4, stream);

  // frag tables + CSR counts/scans
  k_wprep<<<(NFRAG * 64 + 255) / 256, 256, 0, stream>>>(W_ent, mp_Wf, mp_Wb, eu_W, Fhi, Flo);
  k_cnt<<<(M + 255) / 256, 256, 0, stream>>>(ht, cf, cb, M);
  k_scan1<<<nbn, 256, 0, stream>>>(cf, posf, bsumf, N);
  k_qscan<<<1, 256, 0, stream>>>(bsumf, nbn);
  k_scan3<<<nbn, 256, 0, stream>>>(posf, bsumf, N, 0);
  k_scan1<<<nbn, 256, 0, stream>>>(cb, posb, bsumb, N);
  k_qscan<<<1, 256, 0, stream>>>(bsumb, nbn);
  k_scan3<<<nbn, 256, 0, stream>>>(posb, bsumb, N, M);   // bwd section after M fwd slots

  // FUSED: entity encoder (MFMA blocks) + slot scatter (4 edges/thread)
  const int encBlocks = (N + 63) / 64;
  const int slotBlocks = (M + 1023) / 1024;
  k_encslot<<<encBlocks + slotBlocks, 256, 0, stream>>>(ef, Fhi, Flo,
      b_ent, g_ent, be_ent, H0, H, N, encBlocks, ht, rt, posf, posb, si, M);

  // rel-table encoders + packed eu tables
  k_enc<<<(NREL + 15) / 16, 256, 0, stream>>>(rtab, W_ein, b_ein, g_e, be_e, E0t, nullptr, NREL);
  k_tep<<<(NREL + 15) / 16, 256, 0, stream>>>(E0t, eu_W + 64 * 64, eu_b, TEP, NREL);

  const int sgrid = (N + 3) / 4;
  // ---- layer 0 ----
  k_sum<<<sgrid, 256, 0, stream>>>(H, E0t, si, posf, posb, cf, cb, Sall, N);
  k_hupd2mx<<<(N + 63) / 64, 256, 0, stream>>>(H, Sall, cf, cb, Fhi, Flo,
      mp_bf, mp_bb, mp_g, mp_be, HWp, N);

  // ---- layer 1 (eu fused into pull-sum; no E1 buffer) ----
  k_sum2<<<sgrid, 256, 0, stream>>>(H, HWp, TEP, si, posf, posb, cf, cb,
      eu_g, eu_be, Sall, N);

  // qi compaction + query-row E1
  k_qcount<<<nb, 256, 0, stream>>>(q, bcnt, M);
  k_qscan<<<1, 256, 0, stream>>>(bcnt, nb);
  k_qemit<<<nb, 256, 0, stream>>>(q, bcnt, qi, M, NQ);
  k_eu2q<<<(NQ + 3) / 4, 256, 0, stream>>>(HWp, TEP, ht, rt, qi,
      eu_g, eu_be, e1q, NQ);

  // layer-1 H update
  k_hupd2m<<<(N + 63) / 64, 256, 0, stream>>>(H, Sall, cf, cb, Fhi, Flo, FB_L1,
      mp_bf + 64, mp_bb + 64, mp_g + 64, mp_be + 64, N);

  // features + classifier
  k_feat<<<(NQ + 3) / 4, 256, 0, stream>>>(H, H0, e1q, E0t, rt, ht, qi,
      eu_W + 192 * 64, eu_b + 64, eu_g + 64, eu_be + 64, feat, NQ);
  k_cls<<<(NQ + 3) / 4, 256, 0, stream>>>(feat, clsW1, clsb1, clsW2, clsb2,
      (float*)d_out, NQ);
}